// Round 1
// baseline (371.510 us; speedup 1.0000x reference)
//
#include <hip/hip_runtime.h>
#include <stdint.h>

#define HEADS 12
#define DK 64
#define DM 768
#define BT 2
#define SEQ 2048
#define ROWS (BT*SEQ)

typedef __bf16 bf16x4 __attribute__((ext_vector_type(4)));
typedef __bf16 bf16x8 __attribute__((ext_vector_type(8)));
typedef float f32x4 __attribute__((ext_vector_type(4)));

#define SCL2 0.18033688011112042f  /* (1/8) * log2(e) */

__device__ __forceinline__ float exp2fast(float x) {
#if __has_builtin(__builtin_amdgcn_exp2f)
    return __builtin_amdgcn_exp2f(x);
#else
    return exp2f(x);
#endif
}
__device__ __forceinline__ float log2fast(float x) {
#if __has_builtin(__builtin_amdgcn_logf)
    return __builtin_amdgcn_logf(x);
#else
    return log2f(x);
#endif
}

__device__ __forceinline__ uint16_t f2bf(float f) {
    union { float f; uint32_t u; } v; v.f = f;
    uint32_t u = v.u;
    return (uint16_t)((u + 0x7FFFu + ((u >> 16) & 1u)) >> 16);
}

union U8 { uint16_t u[8]; bf16x8 v; };

__device__ __forceinline__ bf16x8 cat44(bf16x4 lo, bf16x4 hi) {
    bf16x8 f;
    f[0] = lo[0]; f[1] = lo[1]; f[2] = lo[2]; f[3] = lo[3];
    f[4] = hi[0]; f[5] = hi[1]; f[6] = hi[2]; f[7] = hi[3];
    return f;
}

// Fragment (16 rows, K=32) from padded row-major LDS tile.
// lane: row = base_row + (lane&15) (already folded into p by caller),
// k = 4*(lane>>4) + {0..3} and +16 (caller folds q*8 bytes into p).
__device__ __forceinline__ bf16x8 ldfrag(const char* p) {
    bf16x4 lo = *(const bf16x4*)p;
    bf16x4 hi = *(const bf16x4*)(p + 32);
    return cat44(lo, hi);
}

// ---------------- convert q/k/v fp32 -> bf16 ----------------
__global__ __launch_bounds__(256) void k_convert(const float* __restrict__ q,
                                                 const float* __restrict__ k,
                                                 const float* __restrict__ v,
                                                 uint16_t* __restrict__ qb,
                                                 uint16_t* __restrict__ kb,
                                                 uint16_t* __restrict__ vb) {
    int z = blockIdx.z;
    const float* src = (z == 0) ? q : (z == 1) ? k : v;
    uint16_t* dst = (z == 0) ? qb : (z == 1) ? kb : vb;
    size_t idx = ((size_t)blockIdx.x * 256 + threadIdx.x) * 4;
    float4 f = *(const float4*)(src + idx);
    ushort4 o;
    o.x = f2bf(f.x); o.y = f2bf(f.y); o.z = f2bf(f.z); o.w = f2bf(f.w);
    *(ushort4*)(dst + idx) = o;
}

// ---------------- W [k][n] fp32 -> Wt [n][k] bf16 ----------------
__global__ __launch_bounds__(256) void k_transpose(const float* __restrict__ Wq,
                                                   const float* __restrict__ Wk,
                                                   const float* __restrict__ Wv,
                                                   const float* __restrict__ Wo,
                                                   uint16_t* __restrict__ Wqt,
                                                   uint16_t* __restrict__ Wkt,
                                                   uint16_t* __restrict__ Wvt,
                                                   uint16_t* __restrict__ Wot) {
    __shared__ float t[32][33];
    int z = blockIdx.z;
    const float* W = (z == 0) ? Wq : (z == 1) ? Wk : (z == 2) ? Wv : Wo;
    uint16_t* Wt = (z == 0) ? Wqt : (z == 1) ? Wkt : (z == 2) ? Wvt : Wot;
    int bx = blockIdx.x * 32;  // k base (W row)
    int by = blockIdx.y * 32;  // n base (W col)
    int tx = threadIdx.x & 31, ty = threadIdx.x >> 5;
#pragma unroll
    for (int r = 0; r < 32; r += 8)
        t[ty + r][tx] = W[(size_t)(bx + ty + r) * DM + by + tx];
    __syncthreads();
#pragma unroll
    for (int r = 0; r < 32; r += 8)
        Wt[(size_t)(by + ty + r) * DM + bx + tx] = f2bf(t[tx][ty + r]);
}

// ---------------- GEMM: C[M=4096][768] = A[4096][768] @ Bt^T + bias ----------------
// A, Bt row-major bf16 (Bt is [n][k]). F32OUT: write float, else bf16.
template <int F32OUT>
__global__ __launch_bounds__(256) void k_gemm(const uint16_t* __restrict__ A,
                                              const uint16_t* __restrict__ Bt,
                                              const float* __restrict__ bias,
                                              void* __restrict__ Cp) {
    __shared__ char smem[2 * 128 * 80];
    char* As = smem;
    char* Bs = smem + 128 * 80;
    const int tid = threadIdx.x, lane = tid & 63, w = tid >> 6;
    const int q = lane >> 4, r16 = lane & 15;
    const int mtile = blockIdx.y * 128, ntile = blockIdx.x * 128;
    const int wm = (w >> 1) * 64, wn = (w & 1) * 64;
    f32x4 acc[4][4] = {};
    for (int k0 = 0; k0 < DM; k0 += 32) {
#pragma unroll
        for (int c = tid; c < 512; c += 256) {
            int row = c >> 2, quad = c & 3;
            *(float4*)(As + row * 80 + quad * 16) =
                *(const float4*)(A + (size_t)(mtile + row) * DM + k0 + quad * 8);
            *(float4*)(Bs + row * 80 + quad * 16) =
                *(const float4*)(Bt + (size_t)(ntile + row) * DM + k0 + quad * 8);
        }
        __syncthreads();
        bf16x8 af[4], bfr[4];
#pragma unroll
        for (int i = 0; i < 4; i++) {
            af[i] = ldfrag(As + (wm + i * 16 + r16) * 80 + q * 8);
            bfr[i] = ldfrag(Bs + (wn + i * 16 + r16) * 80 + q * 8);
        }
#pragma unroll
        for (int mi = 0; mi < 4; mi++)
#pragma unroll
            for (int ni = 0; ni < 4; ni++)
                acc[mi][ni] = __builtin_amdgcn_mfma_f32_16x16x32_bf16(
                    af[mi], bfr[ni], acc[mi][ni], 0, 0, 0);
        __syncthreads();
    }
#pragma unroll
    for (int ni = 0; ni < 4; ni++) {
        int n = ntile + wn + ni * 16 + r16;
        float bv = bias[n];
#pragma unroll
        for (int mi = 0; mi < 4; mi++)
#pragma unroll
            for (int r = 0; r < 4; r++) {
                int m = mtile + wm + mi * 16 + 4 * q + r;
                float val = acc[mi][ni][r] + bv;
                if (F32OUT)
                    ((float*)Cp)[(size_t)m * DM + n] = val;
                else
                    ((uint16_t*)Cp)[(size_t)m * DM + n] = f2bf(val);
            }
    }
}

// ---------------- pass 1: column (query-axis) softmax stats ----------------
// L2out[bh][j] = log2( sum_i 2^(s2[i][j]) ), s2 = (q.k) * SCL2
__global__ __launch_bounds__(256) void k_stats(const uint16_t* __restrict__ Qb,
                                               const uint16_t* __restrict__ Kb,
                                               float* __restrict__ L2out) {
    __shared__ char qs[32 * 144];
    const int tid = threadIdx.x, lane = tid & 63, w = tid >> 6;
    const int q = lane >> 4, r16 = lane & 15;
    const int bh = blockIdx.y, b = bh / HEADS, h = bh % HEADS;
    const int j0 = blockIdx.x * 128 + w * 32;
    const uint16_t* Kbase = Kb + (size_t)b * SEQ * DM + h * DK;
    const uint16_t* Qbase = Qb + (size_t)b * SEQ * DM + h * DK;
    // K fragments (A operand): lane row j = j0 + jf*16 + r16, k = d
    bf16x8 kf[2][2];
#pragma unroll
    for (int jf = 0; jf < 2; jf++) {
        const uint16_t* kp = Kbase + (size_t)(j0 + jf * 16 + r16) * DM + q * 4;
#pragma unroll
        for (int ks = 0; ks < 2; ks++)
            kf[jf][ks] = cat44(*(const bf16x4*)(kp + ks * 32),
                               *(const bf16x4*)(kp + ks * 32 + 16));
    }
    float Ms[2][4], Zs[2][4];
#pragma unroll
    for (int jf = 0; jf < 2; jf++)
#pragma unroll
        for (int r = 0; r < 4; r++) { Ms[jf][r] = -1e30f; Zs[jf][r] = 0.f; }

    for (int i0 = 0; i0 < SEQ; i0 += 32) {
        {
            int row = tid >> 3, oct = tid & 7;
            *(float4*)(qs + row * 144 + oct * 16) =
                *(const float4*)(Qbase + (size_t)(i0 + row) * DM + oct * 8);
        }
        __syncthreads();
        f32x4 st[2][2] = {};
#pragma unroll
        for (int f = 0; f < 2; f++) {
            bf16x8 qf0 = ldfrag(qs + (f * 16 + r16) * 144 + q * 8);
            bf16x8 qf1 = ldfrag(qs + (f * 16 + r16) * 144 + 64 + q * 8);
            st[0][f] = __builtin_amdgcn_mfma_f32_16x16x32_bf16(kf[0][0], qf0, st[0][f], 0, 0, 0);
            st[0][f] = __builtin_amdgcn_mfma_f32_16x16x32_bf16(kf[0][1], qf1, st[0][f], 0, 0, 0);
            st[1][f] = __builtin_amdgcn_mfma_f32_16x16x32_bf16(kf[1][0], qf0, st[1][f], 0, 0, 0);
            st[1][f] = __builtin_amdgcn_mfma_f32_16x16x32_bf16(kf[1][1], qf1, st[1][f], 0, 0, 0);
        }
        __syncthreads();
        // per-lane online update (each lane sees a private i subset; no shuffles here)
#pragma unroll
        for (int jf = 0; jf < 2; jf++)
#pragma unroll
            for (int r = 0; r < 4; r++) {
                float v0 = st[jf][0][r] * SCL2, v1 = st[jf][1][r] * SCL2;
                float Mn = fmaxf(Ms[jf][r], fmaxf(v0, v1));
                Zs[jf][r] = Zs[jf][r] * exp2fast(Ms[jf][r] - Mn) +
                            exp2fast(v0 - Mn) + exp2fast(v1 - Mn);
                Ms[jf][r] = Mn;
            }
    }
    // cross-lane combine over the 16-lane (i-column) group, then write
#pragma unroll
    for (int jf = 0; jf < 2; jf++)
#pragma unroll
        for (int r = 0; r < 4; r++) {
            float Ml = Ms[jf][r], Zl = Zs[jf][r];
            float tm = Ml;
#pragma unroll
            for (int m = 1; m < 16; m <<= 1) tm = fmaxf(tm, __shfl_xor(tm, m));
            float e = Zl * exp2fast(Ml - tm);
#pragma unroll
            for (int m = 1; m < 16; m <<= 1) e += __shfl_xor(e, m);
            if (r16 == 0)
                L2out[(size_t)bh * SEQ + j0 + jf * 16 + 4 * q + r] = tm + log2fast(e);
        }
}

// ---------------- pass 2: X = P @ V with P = 2^(s2 - L2[j]) ----------------
__global__ __launch_bounds__(256) void k_attn(const uint16_t* __restrict__ Qb,
                                              const uint16_t* __restrict__ Kb,
                                              const uint16_t* __restrict__ Vb,
                                              const float* __restrict__ L2,
                                              uint16_t* __restrict__ Xb) {
    __shared__ char lds[4 * 32 * 144];
    char* Ks = lds;
    char* Vs = lds + 4608;
    const int tid = threadIdx.x, lane = tid & 63, w = tid >> 6;
    const int q = lane >> 4, r16 = lane & 15;
    const int bh = blockIdx.y, b = bh / HEADS, h = bh % HEADS;
    const int i0 = blockIdx.x * 128 + w * 32;
    const uint16_t* Qbase = Qb + (size_t)b * SEQ * DM + h * DK;
    const uint16_t* Kbase = Kb + (size_t)b * SEQ * DM + h * DK;
    const uint16_t* Vbase = Vb + (size_t)b * SEQ * DM + h * DK;
    const float* L2b = L2 + (size_t)bh * SEQ;
    // Q fragments (B operand): lane col i = i0 + f*16 + r16, k = d
    bf16x8 qf[2][2];
#pragma unroll
    for (int f = 0; f < 2; f++) {
        const uint16_t* qp = Qbase + (size_t)(i0 + f * 16 + r16) * DM + q * 4;
#pragma unroll
        for (int ks = 0; ks < 2; ks++)
            qf[f][ks] = cat44(*(const bf16x4*)(qp + ks * 32),
                              *(const bf16x4*)(qp + ks * 32 + 16));
    }
    f32x4 xacc[4][2] = {};  // [dc][if] : rows d=dc*16+4q+reg, cols i
    for (int js = 0; js < SEQ; js += 32) {
        {
            int row = tid >> 3, oct = tid & 7;
            *(float4*)(Ks + row * 144 + oct * 16) =
                *(const float4*)(Kbase + (size_t)(js + row) * DM + oct * 8);
            *(float4*)(Vs + row * 144 + oct * 16) =
                *(const float4*)(Vbase + (size_t)(js + row) * DM + oct * 8);
        }
        __syncthreads();
        // s^T tiles: st[jf][if], rows j (4q+reg), cols i (r16)
        f32x4 st[2][2] = {};
#pragma unroll
        for (int jf = 0; jf < 2; jf++) {
            bf16x8 kf0 = ldfrag(Ks + (jf * 16 + r16) * 144 + q * 8);
            bf16x8 kf1 = ldfrag(Ks + (jf * 16 + r16) * 144 + 64 + q * 8);
#pragma unroll
            for (int f = 0; f < 2; f++) {
                st[jf][f] = __builtin_amdgcn_mfma_f32_16x16x32_bf16(kf0, qf[f][0], st[jf][f], 0, 0, 0);
                st[jf][f] = __builtin_amdgcn_mfma_f32_16x16x32_bf16(kf1, qf[f][1], st[jf][f], 0, 0, 0);
            }
        }
        // P^T -> bf16 B-fragments (D-layout of s^T == B-layout for PV)
        float l2v[2][4];
#pragma unroll
        for (int jf = 0; jf < 2; jf++)
#pragma unroll
            for (int r = 0; r < 4; r++)
                l2v[jf][r] = L2b[js + jf * 16 + 4 * q + r];
        bf16x8 pb[2];
#pragma unroll
        for (int f = 0; f < 2; f++) {
            U8 t;
#pragma unroll
            for (int jf = 0; jf < 2; jf++)
#pragma unroll
                for (int r = 0; r < 4; r++)
                    t.u[jf * 4 + r] = f2bf(exp2fast(st[jf][f][r] * SCL2 - l2v[jf][r]));
            pb[f] = t.v;
        }
        // V^T A-fragments from LDS (scalar reads), then PV MFMA
#pragma unroll
        for (int dc = 0; dc < 4; dc++) {
            U8 t;
            const char* vp = Vs + (4 * q) * 144 + (dc * 16 + r16) * 2;
#pragma unroll
            for (int r = 0; r < 4; r++) {
                t.u[r] = *(const uint16_t*)(vp + r * 144);
                t.u[4 + r] = *(const uint16_t*)(vp + 16 * 144 + r * 144);
            }
#pragma unroll
            for (int f = 0; f < 2; f++)
                xacc[dc][f] = __builtin_amdgcn_mfma_f32_16x16x32_bf16(t.v, pb[f], xacc[dc][f], 0, 0, 0);
        }
        __syncthreads();
    }
    // epilogue: transpose X^T (d,i) -> X (i,d) via per-wave LDS region, coalesced store
    char* xr = lds + w * 4608;
#pragma unroll
    for (int dc = 0; dc < 4; dc++)
#pragma unroll
        for (int f = 0; f < 2; f++)
#pragma unroll
            for (int r = 0; r < 4; r++)
                *(uint16_t*)(xr + (f * 16 + r16) * 144 + (dc * 16 + 4 * q + r) * 2) =
                    f2bf(xacc[dc][f][r]);
    __syncthreads();
#pragma unroll
    for (int cc = 0; cc < 4; cc++) {
        int c = cc * 64 + lane;
        int row = c >> 3, oct = c & 7;
        *(float4*)(Xb + (size_t)(b * SEQ + i0 + row) * DM + h * DK + oct * 8) =
            *(const float4*)(xr + row * 144 + oct * 16);
    }
}

extern "C" void kernel_launch(void* const* d_in, const int* in_sizes, int n_in,
                              void* d_out, int out_size, void* d_ws, size_t ws_size,
                              hipStream_t stream) {
    const float* query = (const float*)d_in[0];
    const float* key = (const float*)d_in[1];
    const float* value = (const float*)d_in[2];
    const float* Wq = (const float*)d_in[3];
    const float* bq = (const float*)d_in[4];
    const float* Wk = (const float*)d_in[5];
    const float* bk = (const float*)d_in[6];
    const float* Wv = (const float*)d_in[7];
    const float* bv = (const float*)d_in[8];
    const float* Wo = (const float*)d_in[9];
    const float* bo = (const float*)d_in[10];
    float* out = (float*)d_out;
    char* ws = (char*)d_ws;

    const size_t SZ = (size_t)ROWS * DM * 2;   // 6,291,456 B per bf16 tensor
    const size_t WSZ = (size_t)DM * DM * 2;    // 1,179,648 B per bf16 weight
    uint16_t* qb = (uint16_t*)(ws + 0 * SZ);
    uint16_t* kb = (uint16_t*)(ws + 1 * SZ);
    uint16_t* vb = (uint16_t*)(ws + 2 * SZ);
    uint16_t* Qm = (uint16_t*)(ws + 3 * SZ);
    uint16_t* Km = (uint16_t*)(ws + 4 * SZ);
    uint16_t* Vm = (uint16_t*)(ws + 5 * SZ);
    uint16_t* Xm = (uint16_t*)(ws + 6 * SZ);
    uint16_t* Wqt = (uint16_t*)(ws + 7 * SZ);
    uint16_t* Wkt = (uint16_t*)(ws + 7 * SZ + WSZ);
    uint16_t* Wvt = (uint16_t*)(ws + 7 * SZ + 2 * WSZ);
    uint16_t* Wot = (uint16_t*)(ws + 7 * SZ + 3 * WSZ);
    float* L2buf = (float*)(ws + 7 * SZ + 4 * WSZ);

    k_convert<<<dim3(3072, 1, 3), 256, 0, stream>>>(query, key, value, qb, kb, vb);
    k_transpose<<<dim3(24, 24, 4), 256, 0, stream>>>(Wq, Wk, Wv, Wo, Wqt, Wkt, Wvt, Wot);
    k_gemm<0><<<dim3(6, 32), 256, 0, stream>>>(qb, Wqt, bq, Qm);
    k_gemm<0><<<dim3(6, 32), 256, 0, stream>>>(kb, Wkt, bk, Km);
    k_gemm<0><<<dim3(6, 32), 256, 0, stream>>>(vb, Wvt, bv, Vm);
    k_stats<<<dim3(16, 24), 256, 0, stream>>>(Qm, Km, L2buf);
    k_attn<<<dim3(16, 24), 256, 0, stream>>>(Qm, Km, Vm, L2buf, Xm);
    k_gemm<1><<<dim3(6, 32), 256, 0, stream>>>(Xm, Wot, bo, out);
}

// Round 2
// 312.852 us; speedup vs baseline: 1.1875x; 1.1875x over previous
//
#include <hip/hip_runtime.h>
#include <stdint.h>

#define HEADS 12
#define DK 64
#define DM 768
#define BT 2
#define SEQ 2048
#define ROWS (BT*SEQ)

typedef __bf16 bf16x4 __attribute__((ext_vector_type(4)));
typedef __bf16 bf16x8 __attribute__((ext_vector_type(8)));
typedef float f32x4 __attribute__((ext_vector_type(4)));

#define SCL2 0.18033688011112042f  /* (1/8) * log2(e) */

__device__ __forceinline__ float exp2fast(float x) {
#if __has_builtin(__builtin_amdgcn_exp2f)
    return __builtin_amdgcn_exp2f(x);
#else
    return exp2f(x);
#endif
}
__device__ __forceinline__ float rcpfast(float x) {
#if __has_builtin(__builtin_amdgcn_rcpf)
    return __builtin_amdgcn_rcpf(x);
#else
    return 1.0f / x;
#endif
}

__device__ __forceinline__ uint16_t f2bf(float f) {
    union { float f; uint32_t u; } v; v.f = f;
    uint32_t u = v.u;
    return (uint16_t)((u + 0x7FFFu + ((u >> 16) & 1u)) >> 16);
}
__device__ __forceinline__ float bf2f(uint16_t u) {
    union { uint32_t u; float f; } v; v.u = ((uint32_t)u) << 16;
    return v.f;
}

union U8 { uint16_t u[8]; bf16x8 v; };

__device__ __forceinline__ bf16x8 cat44(bf16x4 lo, bf16x4 hi) {
    bf16x8 f;
    f[0] = lo[0]; f[1] = lo[1]; f[2] = lo[2]; f[3] = lo[3];
    f[4] = hi[0]; f[5] = hi[1]; f[6] = hi[2]; f[7] = hi[3];
    return f;
}

// Fragment (16 rows, K=32) from padded row-major LDS tile: two b64 reads.
__device__ __forceinline__ bf16x8 ldfrag(const char* p) {
    bf16x4 lo = *(const bf16x4*)p;
    bf16x4 hi = *(const bf16x4*)(p + 32);
    return cat44(lo, hi);
}

// ---------------- convert q/k/v fp32 -> bf16 ----------------
__global__ __launch_bounds__(256) void k_convert(const float* __restrict__ q,
                                                 const float* __restrict__ k,
                                                 const float* __restrict__ v,
                                                 uint16_t* __restrict__ qb,
                                                 uint16_t* __restrict__ kb,
                                                 uint16_t* __restrict__ vb) {
    int z = blockIdx.z;
    const float* src = (z == 0) ? q : (z == 1) ? k : v;
    uint16_t* dst = (z == 0) ? qb : (z == 1) ? kb : vb;
    size_t idx = ((size_t)blockIdx.x * 256 + threadIdx.x) * 4;
    float4 f = *(const float4*)(src + idx);
    ushort4 o;
    o.x = f2bf(f.x); o.y = f2bf(f.y); o.z = f2bf(f.z); o.w = f2bf(f.w);
    *(ushort4*)(dst + idx) = o;
}

// ---------------- W [k][n] fp32 -> Wt [n][k] bf16 ----------------
__global__ __launch_bounds__(256) void k_transpose(const float* __restrict__ Wq,
                                                   const float* __restrict__ Wk,
                                                   const float* __restrict__ Wv,
                                                   const float* __restrict__ Wo,
                                                   uint16_t* __restrict__ Wqt,
                                                   uint16_t* __restrict__ Wkt,
                                                   uint16_t* __restrict__ Wvt,
                                                   uint16_t* __restrict__ Wot) {
    __shared__ float t[32][33];
    int z = blockIdx.z;
    const float* W = (z == 0) ? Wq : (z == 1) ? Wk : (z == 2) ? Wv : Wo;
    uint16_t* Wt = (z == 0) ? Wqt : (z == 1) ? Wkt : (z == 2) ? Wvt : Wot;
    int bx = blockIdx.x * 32;
    int by = blockIdx.y * 32;
    int tx = threadIdx.x & 31, ty = threadIdx.x >> 5;
#pragma unroll
    for (int r = 0; r < 32; r += 8)
        t[ty + r][tx] = W[(size_t)(bx + ty + r) * DM + by + tx];
    __syncthreads();
#pragma unroll
    for (int r = 0; r < 32; r += 8)
        Wt[(size_t)(by + ty + r) * DM + bx + tx] = f2bf(t[tx][ty + r]);
}

// ---------------- fused QKV GEMM: z=0 Q, z=1 K (row-major), z=2 V (writes V^T) ----
__global__ __launch_bounds__(256) void k_gemm_qkv(const uint16_t* __restrict__ qb,
                                                  const uint16_t* __restrict__ kb,
                                                  const uint16_t* __restrict__ vb,
                                                  const uint16_t* __restrict__ Wt,  // [2304][768]
                                                  const float* __restrict__ bq,
                                                  const float* __restrict__ bk,
                                                  const float* __restrict__ bv,
                                                  uint16_t* __restrict__ Qm,
                                                  uint16_t* __restrict__ Km,
                                                  uint16_t* __restrict__ VT) {
    __shared__ char smem[2 * 128 * 80];
    char* As = smem;
    char* Bs = smem + 128 * 80;
    const int z = blockIdx.z;
    const uint16_t* A = (z == 0) ? qb : (z == 1) ? kb : vb;
    const uint16_t* Bt = Wt + (size_t)z * DM * DM;
    const float* bias = (z == 0) ? bq : (z == 1) ? bk : bv;
    const int tid = threadIdx.x, lane = tid & 63, w = tid >> 6;
    const int q = lane >> 4, r16 = lane & 15;
    const int mtile = blockIdx.y * 128, ntile = blockIdx.x * 128;
    const int wm = (w >> 1) * 64, wn = (w & 1) * 64;
    f32x4 acc[4][4] = {};
    for (int k0 = 0; k0 < DM; k0 += 32) {
#pragma unroll
        for (int c = tid; c < 512; c += 256) {
            int row = c >> 2, quad = c & 3;
            *(float4*)(As + row * 80 + quad * 16) =
                *(const float4*)(A + (size_t)(mtile + row) * DM + k0 + quad * 8);
            *(float4*)(Bs + row * 80 + quad * 16) =
                *(const float4*)(Bt + (size_t)(ntile + row) * DM + k0 + quad * 8);
        }
        __syncthreads();
        bf16x8 af[4], bfr[4];
#pragma unroll
        for (int i = 0; i < 4; i++) {
            af[i] = ldfrag(As + (wm + i * 16 + r16) * 80 + q * 8);
            bfr[i] = ldfrag(Bs + (wn + i * 16 + r16) * 80 + q * 8);
        }
#pragma unroll
        for (int mi = 0; mi < 4; mi++)
#pragma unroll
            for (int ni = 0; ni < 4; ni++)
                acc[mi][ni] = __builtin_amdgcn_mfma_f32_16x16x32_bf16(
                    af[mi], bfr[ni], acc[mi][ni], 0, 0, 0);
        __syncthreads();
    }
    if (z < 2) {
        uint16_t* out = (z == 0) ? Qm : Km;
#pragma unroll
        for (int ni = 0; ni < 4; ni++) {
            int n = ntile + wn + ni * 16 + r16;
            float bv2 = bias[n];
#pragma unroll
            for (int mi = 0; mi < 4; mi++)
#pragma unroll
                for (int r = 0; r < 4; r++) {
                    int m = mtile + wm + mi * 16 + 4 * q + r;
                    out[(size_t)m * DM + n] = f2bf(acc[mi][ni][r] + bv2);
                }
        }
    } else {
        // V^T layout: VT[((b*HEADS+h)*DK + dk)*SEQ + s]
#pragma unroll
        for (int ni = 0; ni < 4; ni++) {
            int n = ntile + wn + ni * 16 + r16;
            int h = n >> 6, dk = n & 63;
            float bv2 = bias[n];
#pragma unroll
            for (int mi = 0; mi < 4; mi++) {
                int mbase = mtile + wm + mi * 16 + 4 * q;
                int b = mbase >> 11, s = mbase & 2047;
                ushort4 o;
                o.x = f2bf(acc[mi][ni][0] + bv2);
                o.y = f2bf(acc[mi][ni][1] + bv2);
                o.z = f2bf(acc[mi][ni][2] + bv2);
                o.w = f2bf(acc[mi][ni][3] + bv2);
                *(ushort4*)(VT + ((size_t)((b * HEADS + h) * DK + dk)) * SEQ + s) = o;
            }
        }
    }
}

// ---------------- output GEMM (fp32 out) ----------------
__global__ __launch_bounds__(256) void k_gemm_o(const uint16_t* __restrict__ A,
                                                const uint16_t* __restrict__ Bt,
                                                const float* __restrict__ bias,
                                                float* __restrict__ C) {
    __shared__ char smem[2 * 128 * 80];
    char* As = smem;
    char* Bs = smem + 128 * 80;
    const int tid = threadIdx.x, lane = tid & 63, w = tid >> 6;
    const int q = lane >> 4, r16 = lane & 15;
    const int mtile = blockIdx.y * 128, ntile = blockIdx.x * 128;
    const int wm = (w >> 1) * 64, wn = (w & 1) * 64;
    f32x4 acc[4][4] = {};
    for (int k0 = 0; k0 < DM; k0 += 32) {
#pragma unroll
        for (int c = tid; c < 512; c += 256) {
            int row = c >> 2, quad = c & 3;
            *(float4*)(As + row * 80 + quad * 16) =
                *(const float4*)(A + (size_t)(mtile + row) * DM + k0 + quad * 8);
            *(float4*)(Bs + row * 80 + quad * 16) =
                *(const float4*)(Bt + (size_t)(ntile + row) * DM + k0 + quad * 8);
        }
        __syncthreads();
        bf16x8 af[4], bfr[4];
#pragma unroll
        for (int i = 0; i < 4; i++) {
            af[i] = ldfrag(As + (wm + i * 16 + r16) * 80 + q * 8);
            bfr[i] = ldfrag(Bs + (wn + i * 16 + r16) * 80 + q * 8);
        }
#pragma unroll
        for (int mi = 0; mi < 4; mi++)
#pragma unroll
            for (int ni = 0; ni < 4; ni++)
                acc[mi][ni] = __builtin_amdgcn_mfma_f32_16x16x32_bf16(
                    af[mi], bfr[ni], acc[mi][ni], 0, 0, 0);
        __syncthreads();
    }
#pragma unroll
    for (int ni = 0; ni < 4; ni++) {
        int n = ntile + wn + ni * 16 + r16;
        float bv = bias[n];
#pragma unroll
        for (int mi = 0; mi < 4; mi++)
#pragma unroll
            for (int r = 0; r < 4; r++) {
                int m = mtile + wm + mi * 16 + 4 * q + r;
                C[(size_t)m * DM + n] = acc[mi][ni][r] + bv;
            }
    }
}

// ---------------- pass 1: Z[j] = sum_i 2^(s2[i][j]) (no max shift; |s2|<~4) ----
__global__ __launch_bounds__(512, 4) void k_stats(const uint16_t* __restrict__ Qm,
                                                  const uint16_t* __restrict__ Km,
                                                  float* __restrict__ Zbuf) {
    __shared__ char qs[64 * 144];
    const int tid = threadIdx.x, lane = tid & 63, w = tid >> 6;
    const int q = lane >> 4, r16 = lane & 15;
    const int bh = blockIdx.y, b = bh / HEADS, h = bh % HEADS;
    const int j0 = blockIdx.x * 128 + w * 16;
    // K fragments (A operand): lane row j = j0 + r16, k = d
    bf16x8 kf[2];
    {
        const uint16_t* kp = Km + (size_t)(b * SEQ + j0 + r16) * DM + h * DK + q * 4;
#pragma unroll
        for (int ks = 0; ks < 2; ks++)
            kf[ks] = cat44(*(const bf16x4*)(kp + ks * 32),
                           *(const bf16x4*)(kp + ks * 32 + 16));
    }
    float Zs[4] = {0.f, 0.f, 0.f, 0.f};
    const uint16_t* Qbase = Qm + (size_t)b * SEQ * DM + h * DK;
    for (int i0 = 0; i0 < SEQ; i0 += 64) {
        {
            int row = tid >> 3, c16 = tid & 7;
            *(float4*)(qs + row * 144 + c16 * 16) =
                *(const float4*)(Qbase + (size_t)(i0 + row) * DM + c16 * 8);
        }
        __syncthreads();
        f32x4 st[4] = {};
#pragma unroll
        for (int f = 0; f < 4; f++) {
            bf16x8 qf0 = ldfrag(qs + (f * 16 + r16) * 144 + q * 8);
            bf16x8 qf1 = ldfrag(qs + (f * 16 + r16) * 144 + 64 + q * 8);
            st[f] = __builtin_amdgcn_mfma_f32_16x16x32_bf16(kf[0], qf0, st[f], 0, 0, 0);
            st[f] = __builtin_amdgcn_mfma_f32_16x16x32_bf16(kf[1], qf1, st[f], 0, 0, 0);
        }
        __syncthreads();
#pragma unroll
        for (int f = 0; f < 4; f++)
#pragma unroll
            for (int r = 0; r < 4; r++)
                Zs[r] += exp2fast(st[f][r] * SCL2);
    }
    // sum over the 16-lane i-group
#pragma unroll
    for (int r = 0; r < 4; r++) {
        float e = Zs[r];
#pragma unroll
        for (int m = 1; m < 16; m <<= 1) e += __shfl_xor(e, m);
        if (r16 == 0) Zbuf[(size_t)bh * SEQ + j0 + 4 * q + r] = e;
    }
}

// ---------------- scale V^T rows by 1/Z[j] in place ----------------
__global__ __launch_bounds__(256) void k_vscale(uint16_t* __restrict__ VT,
                                                const float* __restrict__ Zbuf) {
    size_t t = (size_t)blockIdx.x * 256 + threadIdx.x;
    size_t base = t * 8;
    int rowid = (int)(base >> 11);      // (bh*64 + d)
    int bh = rowid >> 6;
    int s0 = (int)(base & 2047);
    const float* Zp = Zbuf + (size_t)bh * SEQ + s0;
    float4 z0 = *(const float4*)Zp;
    float4 z1 = *(const float4*)(Zp + 4);
    ushort4 a = *(ushort4*)(VT + base);
    ushort4 c = *(ushort4*)(VT + base + 4);
    ushort4 oa, oc;
    oa.x = f2bf(bf2f(a.x) * rcpfast(z0.x));
    oa.y = f2bf(bf2f(a.y) * rcpfast(z0.y));
    oa.z = f2bf(bf2f(a.z) * rcpfast(z0.z));
    oa.w = f2bf(bf2f(a.w) * rcpfast(z0.w));
    oc.x = f2bf(bf2f(c.x) * rcpfast(z1.x));
    oc.y = f2bf(bf2f(c.y) * rcpfast(z1.y));
    oc.z = f2bf(bf2f(c.z) * rcpfast(z1.z));
    oc.w = f2bf(bf2f(c.w) * rcpfast(z1.w));
    *(ushort4*)(VT + base) = oa;
    *(ushort4*)(VT + base + 4) = oc;
}

// ---------------- pass 2: X = E @ V' with E = 2^(s2) ----------------
__global__ __launch_bounds__(512, 4) void k_attn(const uint16_t* __restrict__ Qm,
                                                 const uint16_t* __restrict__ Km,
                                                 const uint16_t* __restrict__ VT,
                                                 uint16_t* __restrict__ Xm) {
    __shared__ char lds[18432];
    char* Ks = lds;             // [32][144B]
    char* Vs = lds + 4608;      // [64][80B]  (V^T tile: rows d, cols j)
    const int tid = threadIdx.x, lane = tid & 63, w = tid >> 6;
    const int q = lane >> 4, r16 = lane & 15;
    const int bh = blockIdx.y, b = bh / HEADS, h = bh % HEADS;
    const int i0 = blockIdx.x * 128 + w * 16;
    const uint16_t* Qbase = Qm + (size_t)b * SEQ * DM + h * DK;
    const uint16_t* Kbase = Km + (size_t)b * SEQ * DM + h * DK;
    const uint16_t* VTbase = VT + (size_t)bh * DK * SEQ;
    // Q fragments (B operand): lane col i = i0 + r16, k = d
    bf16x8 qf[2];
    {
        const uint16_t* qp = Qbase + (size_t)(i0 + r16) * DM + q * 4;
#pragma unroll
        for (int ks = 0; ks < 2; ks++)
            qf[ks] = cat44(*(const bf16x4*)(qp + ks * 32),
                           *(const bf16x4*)(qp + ks * 32 + 16));
    }
    f32x4 xacc[4] = {};  // [dc] rows d=dc*16+4q+r, cols i=r16
    for (int js = 0; js < SEQ; js += 32) {
        if (tid < 256) {
            int row = tid >> 3, c16 = tid & 7;
            *(float4*)(Ks + row * 144 + c16 * 16) =
                *(const float4*)(Kbase + (size_t)(js + row) * DM + c16 * 8);
        } else {
            int c = tid - 256;
            int row = c >> 2, c16 = c & 3;
            *(float4*)(Vs + row * 80 + c16 * 16) =
                *(const float4*)(VTbase + (size_t)row * SEQ + js + c16 * 8);
        }
        __syncthreads();
        // s^T tiles: st[jf]: rows j=jf*16+4q+r, cols i=r16
        f32x4 st[2] = {};
#pragma unroll
        for (int jf = 0; jf < 2; jf++) {
            bf16x8 kf0 = ldfrag(Ks + (jf * 16 + r16) * 144 + q * 8);
            bf16x8 kf1 = ldfrag(Ks + (jf * 16 + r16) * 144 + 64 + q * 8);
            st[jf] = __builtin_amdgcn_mfma_f32_16x16x32_bf16(kf0, qf[0], st[jf], 0, 0, 0);
            st[jf] = __builtin_amdgcn_mfma_f32_16x16x32_bf16(kf1, qf[1], st[jf], 0, 0, 0);
        }
        // E^T -> bf16 B-fragment for PV (D-layout of s^T == B-layout)
        U8 t8;
#pragma unroll
        for (int jf = 0; jf < 2; jf++)
#pragma unroll
            for (int r = 0; r < 4; r++)
                t8.u[jf * 4 + r] = f2bf(exp2fast(st[jf][r] * SCL2));
        bf16x8 pb = t8.v;
        // V'^T A-fragments from LDS (vector b64 reads), then PV MFMA
#pragma unroll
        for (int dc = 0; dc < 4; dc++) {
            bf16x8 vf = ldfrag(Vs + (dc * 16 + r16) * 80 + q * 8);
            xacc[dc] = __builtin_amdgcn_mfma_f32_16x16x32_bf16(vf, pb, xacc[dc], 0, 0, 0);
        }
        __syncthreads();
    }
    // epilogue: X^T (d,i) -> X (i,d) via per-wave LDS region, coalesced store
    char* xr = lds + w * 2304;  // [16 rows i][136B]
#pragma unroll
    for (int dc = 0; dc < 4; dc++)
#pragma unroll
        for (int r = 0; r < 4; r++)
            *(uint16_t*)(xr + r16 * 136 + (dc * 16 + 4 * q + r) * 2) = f2bf(xacc[dc][r]);
    __syncthreads();
#pragma unroll
    for (int cc = 0; cc < 2; cc++) {
        int c = cc * 64 + lane;
        int row = c >> 3, c16 = c & 7;
        *(float4*)(Xm + (size_t)(b * SEQ + i0 + row) * DM + h * DK + c16 * 8) =
            *(const float4*)(xr + row * 136 + c16 * 16);
    }
}

extern "C" void kernel_launch(void* const* d_in, const int* in_sizes, int n_in,
                              void* d_out, int out_size, void* d_ws, size_t ws_size,
                              hipStream_t stream) {
    const float* query = (const float*)d_in[0];
    const float* key = (const float*)d_in[1];
    const float* value = (const float*)d_in[2];
    const float* Wq = (const float*)d_in[3];
    const float* bq = (const float*)d_in[4];
    const float* Wk = (const float*)d_in[5];
    const float* bk = (const float*)d_in[6];
    const float* Wv = (const float*)d_in[7];
    const float* bv = (const float*)d_in[8];
    const float* Wo = (const float*)d_in[9];
    const float* bo = (const float*)d_in[10];
    float* out = (float*)d_out;
    char* ws = (char*)d_ws;

    const size_t SZ = (size_t)ROWS * DM * 2;   // bf16 activation tensor bytes
    const size_t WSZ = (size_t)DM * DM * 2;    // bf16 weight bytes
    uint16_t* qb = (uint16_t*)(ws + 0 * SZ);
    uint16_t* kb = (uint16_t*)(ws + 1 * SZ);
    uint16_t* vb = (uint16_t*)(ws + 2 * SZ);
    uint16_t* Qm = (uint16_t*)(ws + 3 * SZ);
    uint16_t* Km = (uint16_t*)(ws + 4 * SZ);
    uint16_t* VT = (uint16_t*)(ws + 5 * SZ);
    uint16_t* Xm = (uint16_t*)(ws + 6 * SZ);
    uint16_t* Wqt = (uint16_t*)(ws + 7 * SZ);            // Wqt,Wkt,Wvt contiguous
    uint16_t* Wkt = (uint16_t*)(ws + 7 * SZ + WSZ);
    uint16_t* Wvt = (uint16_t*)(ws + 7 * SZ + 2 * WSZ);
    uint16_t* Wot = (uint16_t*)(ws + 7 * SZ + 3 * WSZ);
    float* Zbuf = (float*)(ws + 7 * SZ + 4 * WSZ);       // [24][2048] f32

    k_convert<<<dim3(3072, 1, 3), 256, 0, stream>>>(query, key, value, qb, kb, vb);
    k_transpose<<<dim3(24, 24, 4), 256, 0, stream>>>(Wq, Wk, Wv, Wo, Wqt, Wkt, Wvt, Wot);
    k_gemm_qkv<<<dim3(6, 32, 3), 256, 0, stream>>>(qb, kb, vb, Wqt, bq, bk, bv, Qm, Km, VT);
    k_stats<<<dim3(16, 24), 512, 0, stream>>>(Qm, Km, Zbuf);
    k_vscale<<<dim3(1536), 256, 0, stream>>>(VT, Zbuf);
    k_attn<<<dim3(16, 24), 512, 0, stream>>>(Qm, Km, VT, Xm);
    k_gemm_o<<<dim3(6, 32), 256, 0, stream>>>(Xm, Wot, bo, out);
}

// Round 3
// 275.867 us; speedup vs baseline: 1.3467x; 1.1341x over previous
//
#include <hip/hip_runtime.h>
#include <stdint.h>

#define HEADS 12
#define DK 64
#define DM 768
#define BT 2
#define SEQ 2048
#define ROWS (BT*SEQ)

typedef __bf16 bf16x4 __attribute__((ext_vector_type(4)));
typedef __bf16 bf16x8 __attribute__((ext_vector_type(8)));
typedef float f32x4 __attribute__((ext_vector_type(4)));

#define SCL2 0.18033688011112042f  /* (1/8) * log2(e) */

__device__ __forceinline__ float exp2fast(float x) {
#if __has_builtin(__builtin_amdgcn_exp2f)
    return __builtin_amdgcn_exp2f(x);
#else
    return exp2f(x);
#endif
}
__device__ __forceinline__ float rcpfast(float x) {
#if __has_builtin(__builtin_amdgcn_rcpf)
    return __builtin_amdgcn_rcpf(x);
#else
    return 1.0f / x;
#endif
}

__device__ __forceinline__ uint16_t f2bf(float f) {
    union { float f; uint32_t u; } v; v.f = f;
    uint32_t u = v.u;
    return (uint16_t)((u + 0x7FFFu + ((u >> 16) & 1u)) >> 16);
}
__device__ __forceinline__ float bf2f(uint16_t u) {
    union { uint32_t u; float f; } v; v.u = ((uint32_t)u) << 16;
    return v.f;
}

union U8 { uint16_t u[8]; bf16x8 v; float4 f; };

__device__ __forceinline__ bf16x8 cat44(bf16x4 lo, bf16x4 hi) {
    bf16x8 f;
    f[0] = lo[0]; f[1] = lo[1]; f[2] = lo[2]; f[3] = lo[3];
    f[4] = hi[0]; f[5] = hi[1]; f[6] = hi[2]; f[7] = hi[3];
    return f;
}

// Fragment (16 rows, K=32) from padded row-major LDS tile: two b64 reads.
__device__ __forceinline__ bf16x8 ldfrag(const char* p) {
    bf16x4 lo = *(const bf16x4*)p;
    bf16x4 hi = *(const bf16x4*)(p + 32);
    return cat44(lo, hi);
}

// ---------------- W [k][n] fp32 -> Wt [n][k] bf16 ----------------
__global__ __launch_bounds__(256) void k_transpose(const float* __restrict__ Wq,
                                                   const float* __restrict__ Wk,
                                                   const float* __restrict__ Wv,
                                                   const float* __restrict__ Wo,
                                                   uint16_t* __restrict__ Wqt,
                                                   uint16_t* __restrict__ Wkt,
                                                   uint16_t* __restrict__ Wvt,
                                                   uint16_t* __restrict__ Wot) {
    __shared__ float t[32][33];
    int z = blockIdx.z;
    const float* W = (z == 0) ? Wq : (z == 1) ? Wk : (z == 2) ? Wv : Wo;
    uint16_t* Wt = (z == 0) ? Wqt : (z == 1) ? Wkt : (z == 2) ? Wvt : Wot;
    int bx = blockIdx.x * 32;
    int by = blockIdx.y * 32;
    int tx = threadIdx.x & 31, ty = threadIdx.x >> 5;
#pragma unroll
    for (int r = 0; r < 32; r += 8)
        t[ty + r][tx] = W[(size_t)(bx + ty + r) * DM + by + tx];
    __syncthreads();
#pragma unroll
    for (int r = 0; r < 32; r += 8)
        Wt[(size_t)(by + ty + r) * DM + bx + tx] = f2bf(t[tx][ty + r]);
}

// ---------------- fused QKV GEMM (fp32 A converted in staging) ----------------
// z=0: Q row-major bf16; z=1: K row-major bf16; z=2: V -> V^T scatter.
__global__ __launch_bounds__(256) void k_gemm_qkv(const float* __restrict__ Aq,
                                                  const float* __restrict__ Ak,
                                                  const float* __restrict__ Av,
                                                  const uint16_t* __restrict__ Wt,
                                                  const float* __restrict__ bq,
                                                  const float* __restrict__ bk,
                                                  const float* __restrict__ bv,
                                                  uint16_t* __restrict__ Qm,
                                                  uint16_t* __restrict__ Km,
                                                  uint16_t* __restrict__ VT) {
    __shared__ char smem[2 * 2 * 128 * 80];  // [buf][A|B][128][80B]
    const int z = blockIdx.z;
    const float* A = (z == 0) ? Aq : (z == 1) ? Ak : Av;
    const uint16_t* Bt = Wt + (size_t)z * DM * DM;
    const float* bias = (z == 0) ? bq : (z == 1) ? bk : bv;
    const int tid = threadIdx.x, lane = tid & 63, w = tid >> 6;
    const int q = lane >> 4, r16 = lane & 15;
    const int mtile = blockIdx.y * 128, ntile = blockIdx.x * 128;
    const int wm = (w >> 1) * 64, wn = (w & 1) * 64;
    const int srow = tid >> 1, shalf = tid & 1;
    const float* ap = A + (size_t)(mtile + srow) * DM + shalf * 16;
    const uint16_t* bp = Bt + (size_t)(ntile + srow) * DM + shalf * 16;
    f32x4 acc[4][4] = {};
    float4 ra0 = *(const float4*)(ap + 0);
    float4 ra1 = *(const float4*)(ap + 4);
    float4 ra2 = *(const float4*)(ap + 8);
    float4 ra3 = *(const float4*)(ap + 12);
    float4 rb0 = *(const float4*)(bp + 0);
    float4 rb1 = *(const float4*)((const char*)bp + 16);
    for (int t = 0; t < 24; ++t) {
        char* As = smem + (t & 1) * 20480;
        char* Bs = As + 10240;
        U8 pk0, pk1;
        pk0.u[0] = f2bf(ra0.x); pk0.u[1] = f2bf(ra0.y); pk0.u[2] = f2bf(ra0.z); pk0.u[3] = f2bf(ra0.w);
        pk0.u[4] = f2bf(ra1.x); pk0.u[5] = f2bf(ra1.y); pk0.u[6] = f2bf(ra1.z); pk0.u[7] = f2bf(ra1.w);
        pk1.u[0] = f2bf(ra2.x); pk1.u[1] = f2bf(ra2.y); pk1.u[2] = f2bf(ra2.z); pk1.u[3] = f2bf(ra2.w);
        pk1.u[4] = f2bf(ra3.x); pk1.u[5] = f2bf(ra3.y); pk1.u[6] = f2bf(ra3.z); pk1.u[7] = f2bf(ra3.w);
        *(float4*)(As + srow * 80 + shalf * 32) = pk0.f;
        *(float4*)(As + srow * 80 + shalf * 32 + 16) = pk1.f;
        *(float4*)(Bs + srow * 80 + shalf * 32) = rb0;
        *(float4*)(Bs + srow * 80 + shalf * 32 + 16) = rb1;
        if (t < 23) {
            const float* ap2 = ap + (t + 1) * 32;
            ra0 = *(const float4*)(ap2 + 0);
            ra1 = *(const float4*)(ap2 + 4);
            ra2 = *(const float4*)(ap2 + 8);
            ra3 = *(const float4*)(ap2 + 12);
            const uint16_t* bp2 = bp + (t + 1) * 32;
            rb0 = *(const float4*)bp2;
            rb1 = *(const float4*)((const char*)bp2 + 16);
        }
        __syncthreads();
        bf16x8 af[4], bfr[4];
#pragma unroll
        for (int i = 0; i < 4; i++) {
            af[i] = ldfrag(As + (wm + i * 16 + r16) * 80 + q * 8);
            bfr[i] = ldfrag(Bs + (wn + i * 16 + r16) * 80 + q * 8);
        }
#pragma unroll
        for (int mi = 0; mi < 4; mi++)
#pragma unroll
            for (int ni = 0; ni < 4; ni++)
                acc[mi][ni] = __builtin_amdgcn_mfma_f32_16x16x32_bf16(
                    af[mi], bfr[ni], acc[mi][ni], 0, 0, 0);
    }
    if (z < 2) {
        uint16_t* out = (z == 0) ? Qm : Km;
#pragma unroll
        for (int ni = 0; ni < 4; ni++) {
            int n = ntile + wn + ni * 16 + r16;
            float bv2 = bias[n];
#pragma unroll
            for (int mi = 0; mi < 4; mi++)
#pragma unroll
                for (int r = 0; r < 4; r++) {
                    int m = mtile + wm + mi * 16 + 4 * q + r;
                    out[(size_t)m * DM + n] = f2bf(acc[mi][ni][r] + bv2);
                }
        }
    } else {
        // V^T layout: VT[((b*HEADS+h)*DK + dk)*SEQ + s]
#pragma unroll
        for (int ni = 0; ni < 4; ni++) {
            int n = ntile + wn + ni * 16 + r16;
            int h = n >> 6, dk = n & 63;
            float bv2 = bias[n];
#pragma unroll
            for (int mi = 0; mi < 4; mi++) {
                int mbase = mtile + wm + mi * 16 + 4 * q;
                int b = mbase >> 11, s = mbase & 2047;
                ushort4 o;
                o.x = f2bf(acc[mi][ni][0] + bv2);
                o.y = f2bf(acc[mi][ni][1] + bv2);
                o.z = f2bf(acc[mi][ni][2] + bv2);
                o.w = f2bf(acc[mi][ni][3] + bv2);
                *(ushort4*)(VT + ((size_t)((b * HEADS + h) * DK + dk)) * SEQ + s) = o;
            }
        }
    }
}

// ---------------- output GEMM (bf16 A, fp32 out) ----------------
__global__ __launch_bounds__(256) void k_gemm_o(const uint16_t* __restrict__ A,
                                                const uint16_t* __restrict__ Bt,
                                                const float* __restrict__ bias,
                                                float* __restrict__ C) {
    __shared__ char smem[2 * 2 * 128 * 80];
    const int tid = threadIdx.x, lane = tid & 63, w = tid >> 6;
    const int q = lane >> 4, r16 = lane & 15;
    const int mtile = blockIdx.y * 128, ntile = blockIdx.x * 128;
    const int wm = (w >> 1) * 64, wn = (w & 1) * 64;
    const int srow = tid >> 1, shalf = tid & 1;
    const uint16_t* ap = A + (size_t)(mtile + srow) * DM + shalf * 16;
    const uint16_t* bp = Bt + (size_t)(ntile + srow) * DM + shalf * 16;
    f32x4 acc[4][4] = {};
    float4 ra0 = *(const float4*)ap;
    float4 ra1 = *(const float4*)((const char*)ap + 16);
    float4 rb0 = *(const float4*)bp;
    float4 rb1 = *(const float4*)((const char*)bp + 16);
    for (int t = 0; t < 24; ++t) {
        char* As = smem + (t & 1) * 20480;
        char* Bs = As + 10240;
        *(float4*)(As + srow * 80 + shalf * 32) = ra0;
        *(float4*)(As + srow * 80 + shalf * 32 + 16) = ra1;
        *(float4*)(Bs + srow * 80 + shalf * 32) = rb0;
        *(float4*)(Bs + srow * 80 + shalf * 32 + 16) = rb1;
        if (t < 23) {
            const uint16_t* ap2 = ap + (t + 1) * 32;
            ra0 = *(const float4*)ap2;
            ra1 = *(const float4*)((const char*)ap2 + 16);
            const uint16_t* bp2 = bp + (t + 1) * 32;
            rb0 = *(const float4*)bp2;
            rb1 = *(const float4*)((const char*)bp2 + 16);
        }
        __syncthreads();
        bf16x8 af[4], bfr[4];
#pragma unroll
        for (int i = 0; i < 4; i++) {
            af[i] = ldfrag(As + (wm + i * 16 + r16) * 80 + q * 8);
            bfr[i] = ldfrag(Bs + (wn + i * 16 + r16) * 80 + q * 8);
        }
#pragma unroll
        for (int mi = 0; mi < 4; mi++)
#pragma unroll
            for (int ni = 0; ni < 4; ni++)
                acc[mi][ni] = __builtin_amdgcn_mfma_f32_16x16x32_bf16(
                    af[mi], bfr[ni], acc[mi][ni], 0, 0, 0);
    }
#pragma unroll
    for (int ni = 0; ni < 4; ni++) {
        int n = ntile + wn + ni * 16 + r16;
        float bv = bias[n];
#pragma unroll
        for (int mi = 0; mi < 4; mi++)
#pragma unroll
            for (int r = 0; r < 4; r++) {
                int m = mtile + wm + mi * 16 + 4 * q + r;
                C[(size_t)m * DM + n] = acc[mi][ni][r] + bv;
            }
    }
}

// ---------------- pass 1: Z[j] = sum_i 2^(s2[i][j]) (no max shift; |s2| small) ----
__global__ __launch_bounds__(512, 4) void k_stats(const uint16_t* __restrict__ Qm,
                                                  const uint16_t* __restrict__ Km,
                                                  float* __restrict__ Zbuf) {
    __shared__ char lds[2 * 9216];
    const int tid = threadIdx.x, lane = tid & 63, w = tid >> 6;
    const int q = lane >> 4, r16 = lane & 15;
    const int bh = blockIdx.y, b = bh / HEADS, h = bh % HEADS;
    const int j0 = blockIdx.x * 128 + w * 16;
    bf16x8 kf[2];
    {
        const uint16_t* kp = Km + (size_t)(b * SEQ + j0 + r16) * DM + h * DK + q * 4;
#pragma unroll
        for (int ks = 0; ks < 2; ks++)
            kf[ks] = cat44(*(const bf16x4*)(kp + ks * 32),
                           *(const bf16x4*)(kp + ks * 32 + 16));
    }
    const uint16_t* Qbase = Qm + (size_t)b * SEQ * DM + h * DK;
    const int srow = tid >> 3, sseg = tid & 7;
    float4 rq = *(const float4*)(Qbase + (size_t)srow * DM + sseg * 8);
    float Zs[4] = {0.f, 0.f, 0.f, 0.f};
    for (int t = 0; t < 32; ++t) {
        char* Qs = lds + (t & 1) * 9216;
        *(float4*)(Qs + srow * 144 + sseg * 16) = rq;
        if (t < 31)
            rq = *(const float4*)(Qbase + (size_t)((t + 1) * 64 + srow) * DM + sseg * 8);
        __syncthreads();
        f32x4 st[4] = {};
#pragma unroll
        for (int f = 0; f < 4; f++) {
            bf16x8 qf0 = ldfrag(Qs + (f * 16 + r16) * 144 + q * 8);
            bf16x8 qf1 = ldfrag(Qs + (f * 16 + r16) * 144 + 64 + q * 8);
            st[f] = __builtin_amdgcn_mfma_f32_16x16x32_bf16(kf[0], qf0, st[f], 0, 0, 0);
            st[f] = __builtin_amdgcn_mfma_f32_16x16x32_bf16(kf[1], qf1, st[f], 0, 0, 0);
        }
#pragma unroll
        for (int f = 0; f < 4; f++)
#pragma unroll
            for (int r = 0; r < 4; r++)
                Zs[r] += exp2fast(st[f][r] * SCL2);
    }
#pragma unroll
    for (int r = 0; r < 4; r++) {
        float e = Zs[r];
#pragma unroll
        for (int m = 1; m < 16; m <<= 1) e += __shfl_xor(e, m);
        if (r16 == 0) Zbuf[(size_t)bh * SEQ + j0 + 4 * q + r] = e;
    }
}

// ---------------- scale V^T rows by 1/Z[j] in place ----------------
__global__ __launch_bounds__(256) void k_vscale(uint16_t* __restrict__ VT,
                                                const float* __restrict__ Zbuf) {
    size_t t = (size_t)blockIdx.x * 256 + threadIdx.x;
    size_t base = t * 8;
    int rowid = (int)(base >> 11);
    int bh = rowid >> 6;
    int s0 = (int)(base & 2047);
    const float* Zp = Zbuf + (size_t)bh * SEQ + s0;
    float4 z0 = *(const float4*)Zp;
    float4 z1 = *(const float4*)(Zp + 4);
    ushort4 a = *(ushort4*)(VT + base);
    ushort4 c = *(ushort4*)(VT + base + 4);
    ushort4 oa, oc;
    oa.x = f2bf(bf2f(a.x) * rcpfast(z0.x));
    oa.y = f2bf(bf2f(a.y) * rcpfast(z0.y));
    oa.z = f2bf(bf2f(a.z) * rcpfast(z0.z));
    oa.w = f2bf(bf2f(a.w) * rcpfast(z0.w));
    oc.x = f2bf(bf2f(c.x) * rcpfast(z1.x));
    oc.y = f2bf(bf2f(c.y) * rcpfast(z1.y));
    oc.z = f2bf(bf2f(c.z) * rcpfast(z1.z));
    oc.w = f2bf(bf2f(c.w) * rcpfast(z1.w));
    *(ushort4*)(VT + base) = oa;
    *(ushort4*)(VT + base + 4) = oc;
}

// ---------------- pass 2: X = E @ V' with E = 2^(s2), KVBLK=64, dbuf ----------------
__global__ __launch_bounds__(512, 4) void k_attn(const uint16_t* __restrict__ Qm,
                                                 const uint16_t* __restrict__ Km,
                                                 const uint16_t* __restrict__ VT,
                                                 uint16_t* __restrict__ Xm) {
    __shared__ char lds[2 * 18432];  // [buf][ K[64][144] | V^T[64][144] ]
    const int tid = threadIdx.x, lane = tid & 63, w = tid >> 6;
    const int q = lane >> 4, r16 = lane & 15;
    const int bh = blockIdx.y, b = bh / HEADS, h = bh % HEADS;
    const int i0 = blockIdx.x * 128 + w * 16;
    const uint16_t* Qbase = Qm + (size_t)b * SEQ * DM + h * DK;
    const uint16_t* Kbase = Km + (size_t)b * SEQ * DM + h * DK;
    const uint16_t* VTbase = VT + (size_t)bh * DK * SEQ;
    // Q fragments (B operand): lane col i = i0 + r16, k = d
    bf16x8 qf[2];
    {
        const uint16_t* qp = Qbase + (size_t)(i0 + r16) * DM + q * 4;
#pragma unroll
        for (int ks = 0; ks < 2; ks++)
            qf[ks] = cat44(*(const bf16x4*)(qp + ks * 32),
                           *(const bf16x4*)(qp + ks * 32 + 16));
    }
    const int srow = tid >> 3, sseg = tid & 7;  // 64 rows x 128B, 16B per thread
    float4 rk = *(const float4*)(Kbase + (size_t)srow * DM + sseg * 8);
    float4 rv = *(const float4*)(VTbase + (size_t)srow * SEQ + sseg * 8);
    f32x4 xacc[4] = {};  // [dc] rows d=dc*16+4q+r, cols i=r16
    for (int t = 0; t < 32; ++t) {
        char* Ks = lds + (t & 1) * 18432;
        char* Vs = Ks + 9216;
        *(float4*)(Ks + srow * 144 + sseg * 16) = rk;
        *(float4*)(Vs + srow * 144 + sseg * 16) = rv;
        if (t < 31) {
            int js = (t + 1) * 64;
            rk = *(const float4*)(Kbase + (size_t)(js + srow) * DM + sseg * 8);
            rv = *(const float4*)(VTbase + (size_t)srow * SEQ + js + sseg * 8);
        }
        __syncthreads();
        // s^T: st[jf]: rows j=jf*16+4q+r, cols i=r16
        f32x4 st[4] = {};
#pragma unroll
        for (int jf = 0; jf < 4; jf++) {
            bf16x8 kf0 = ldfrag(Ks + (jf * 16 + r16) * 144 + q * 8);
            bf16x8 kf1 = ldfrag(Ks + (jf * 16 + r16) * 144 + 64 + q * 8);
            st[jf] = __builtin_amdgcn_mfma_f32_16x16x32_bf16(kf0, qf[0], st[jf], 0, 0, 0);
            st[jf] = __builtin_amdgcn_mfma_f32_16x16x32_bf16(kf1, qf[1], st[jf], 0, 0, 0);
        }
        // E^T -> bf16 B-fragments (one per 32-j chunk)
        bf16x8 pb[2];
#pragma unroll
        for (int c = 0; c < 2; c++) {
            U8 t8;
#pragma unroll
            for (int r = 0; r < 4; r++) {
                t8.u[r] = f2bf(exp2fast(st[2 * c][r] * SCL2));
                t8.u[4 + r] = f2bf(exp2fast(st[2 * c + 1][r] * SCL2));
            }
            pb[c] = t8.v;
        }
        // V'^T A-fragments, PV MFMA
#pragma unroll
        for (int dc = 0; dc < 4; dc++)
#pragma unroll
            for (int c = 0; c < 2; c++) {
                bf16x8 vf = ldfrag(Vs + (dc * 16 + r16) * 144 + c * 64 + q * 8);
                xacc[dc] = __builtin_amdgcn_mfma_f32_16x16x32_bf16(vf, pb[c], xacc[dc], 0, 0, 0);
            }
    }
    __syncthreads();
    // epilogue: X^T (d,i) -> X (i,d) via per-wave LDS region, coalesced store
    char* xr = lds + w * 2304;  // [16 rows i][136B]
#pragma unroll
    for (int dc = 0; dc < 4; dc++)
#pragma unroll
        for (int r = 0; r < 4; r++)
            *(uint16_t*)(xr + r16 * 136 + (dc * 16 + 4 * q + r) * 2) = f2bf(xacc[dc][r]);
#pragma unroll
    for (int cc = 0; cc < 2; cc++) {
        int c = cc * 64 + lane;
        int row = c >> 3, c16 = c & 7;
        *(float4*)(Xm + (size_t)(b * SEQ + i0 + row) * DM + h * DK + c16 * 8) =
            *(const float4*)(xr + row * 136 + c16 * 16);
    }
}

extern "C" void kernel_launch(void* const* d_in, const int* in_sizes, int n_in,
                              void* d_out, int out_size, void* d_ws, size_t ws_size,
                              hipStream_t stream) {
    const float* query = (const float*)d_in[0];
    const float* key = (const float*)d_in[1];
    const float* value = (const float*)d_in[2];
    const float* Wq = (const float*)d_in[3];
    const float* bq = (const float*)d_in[4];
    const float* Wk = (const float*)d_in[5];
    const float* bk = (const float*)d_in[6];
    const float* Wv = (const float*)d_in[7];
    const float* bv = (const float*)d_in[8];
    const float* Wo = (const float*)d_in[9];
    const float* bo = (const float*)d_in[10];
    float* out = (float*)d_out;
    char* ws = (char*)d_ws;

    const size_t SZ = (size_t)ROWS * DM * 2;   // bf16 activation tensor bytes
    const size_t WSZ = (size_t)DM * DM * 2;    // bf16 weight bytes
    uint16_t* Qm = (uint16_t*)(ws + 0 * SZ);
    uint16_t* Km = (uint16_t*)(ws + 1 * SZ);
    uint16_t* VT = (uint16_t*)(ws + 2 * SZ);
    uint16_t* Xm = (uint16_t*)(ws + 3 * SZ);
    uint16_t* Wqt = (uint16_t*)(ws + 4 * SZ);            // Wqt,Wkt,Wvt contiguous
    uint16_t* Wkt = (uint16_t*)(ws + 4 * SZ + WSZ);
    uint16_t* Wvt = (uint16_t*)(ws + 4 * SZ + 2 * WSZ);
    uint16_t* Wot = (uint16_t*)(ws + 4 * SZ + 3 * WSZ);
    float* Zbuf = (float*)(ws + 4 * SZ + 4 * WSZ);       // [24][2048] f32

    k_transpose<<<dim3(24, 24, 4), 256, 0, stream>>>(Wq, Wk, Wv, Wo, Wqt, Wkt, Wvt, Wot);
    k_gemm_qkv<<<dim3(6, 32, 3), 256, 0, stream>>>(query, key, value, Wqt, bq, bk, bv, Qm, Km, VT);
    k_stats<<<dim3(16, 24), 512, 0, stream>>>(Qm, Km, Zbuf);
    k_vscale<<<dim3(1536), 256, 0, stream>>>(VT, Zbuf);
    k_attn<<<dim3(16, 24), 512, 0, stream>>>(Qm, Km, VT, Xm);
    k_gemm_o<<<dim3(6, 32), 256, 0, stream>>>(Xm, Wot, bo, out);
}